// Round 11
// baseline (300.406 us; speedup 1.0000x reference)
//
#include <hip/hip_runtime.h>

typedef __bf16 bf16;
typedef bf16 bf16x4 __attribute__((ext_vector_type(4)));
typedef bf16 bf16x8 __attribute__((ext_vector_type(8)));
typedef float f32x4 __attribute__((ext_vector_type(4)));

#define CH 256
#define HH 56
#define WW 56
#define HW 3136
#define MM 12544
#define KT 2304

__device__ __forceinline__ void gll16(const bf16* g, bf16* l) {
  __builtin_amdgcn_global_load_lds(
      (const __attribute__((address_space(1))) void*)g,
      (__attribute__((address_space(3))) void*)l, 16, 0, 0);
}

template <int N>
__device__ __forceinline__ void waitvm() {
  if constexpr (N == 0) asm volatile("s_waitcnt vmcnt(0)" ::: "memory");
  else if constexpr (N == 2) asm volatile("s_waitcnt vmcnt(2)" ::: "memory");
}

// ---------------- NCHW fp32 -> NHWC bf16 ----------------
__global__ __launch_bounds__(256) void nchw2nhwc_k(const float* __restrict__ x,
                                                   bf16* __restrict__ o) {
  __shared__ float t[32][33];
  const int b = blockIdx.z, hw0 = blockIdx.x * 32, c0 = blockIdx.y * 32;
  const int tid = threadIdx.x;
  {
    const int cl = tid >> 3, hwl = (tid & 7) * 4;
    f32x4 v = *(const f32x4*)&x[(size_t)(b * CH + c0 + cl) * HW + hw0 + hwl];
#pragma unroll
    for (int i = 0; i < 4; ++i) t[cl][hwl + i] = v[i];
  }
  __syncthreads();
  const int hwl = tid >> 3, cl = (tid & 7) * 4;
  bf16x4 ov;
#pragma unroll
  for (int i = 0; i < 4; ++i) ov[i] = (bf16)t[cl + i][hwl];
  *(bf16x4*)&o[(size_t)(b * HW + hw0 + hwl) * CH + c0 + cl] = ov;
}

// ---------------- all weight reorders in one launch ----------------
__global__ void reorder_all_k(const float* __restrict__ w1,
                              const float* __restrict__ w2,
                              const float* __restrict__ woff,
                              bf16* __restrict__ w1t, bf16* __restrict__ w2t,
                              bf16* __restrict__ wof) {
  const int gid = blockIdx.x;
  if (gid < 4608) {
    const int idx = gid * 256 + threadIdx.x;
    const float* in = (gid < 2304) ? w1 : w2;
    bf16* out = (gid < 2304) ? w1t : w2t;
    const int li = (gid < 2304) ? idx : idx - 2304 * 256;
    const int o = li / KT, r = li - o * KT;
    const int k = r >> 8, c = r & 255;
    out[li] = (bf16)in[(size_t)(o * CH + c) * 9 + k];
  } else {
    const int li = (gid - 4608) * 256 + threadIdx.x;
    const int o = li / KT, r = li - o * KT;
    const int k = r >> 8, c = r & 255;
    wof[li] = (bf16)((o < 18) ? woff[(size_t)(o * CH + c) * 9 + k] : 0.f);
  }
}

// ---------------- deform sample: 16 rows/block, contiguous-line writes -------
__global__ __launch_bounds__(256) void build_deform_k(
    const bf16* __restrict__ xn, const float* __restrict__ offb,
    const float* __restrict__ boff, bf16* __restrict__ A1) {
  const int tid = threadIdx.x;
  const int m = blockIdx.x * 16 + (tid >> 4);
  const int l15 = tid & 15;
  const int b = m / HW, hw = m - b * HW;
  const int h = hw / WW, w = hw - h * WW;
  const float* orow = offb + m * 18;
  const bf16* xb = xn + (size_t)b * HW * CH;
  bf16* dst = A1 + (size_t)m * KT;
  for (int tap = 0; tap < 9; ++tap) {
    const int ky = tap / 3, kx = tap - ky * 3;
    const float dy = orow[2 * tap] + boff[2 * tap];
    const float dx = orow[2 * tap + 1] + boff[2 * tap + 1];
    const float py = (float)(h + ky * 2 - 2) + dy;
    const float px = (float)(w + kx * 2 - 2) + dx;
    const float y0f = floorf(py), x0f = floorf(px);
    const int y0 = (int)y0f, x0 = (int)x0f;
    const float wy = py - y0f, wx = px - x0f;
    const float w00 = (1.f - wy) * (1.f - wx), w01 = (1.f - wy) * wx;
    const float w10 = wy * (1.f - wx), w11 = wy * wx;
    const bool vy0 = (unsigned)y0 < HH, vy1 = (unsigned)(y0 + 1) < HH;
    const bool vx0 = (unsigned)x0 < WW, vx1 = (unsigned)(x0 + 1) < WW;
    const bf16* p00 = xb + (long long)(y0 * WW + x0) * CH;
#pragma unroll
    for (int j = 0; j < 2; ++j) {
      const int cc = j * 128 + l15 * 8;  // lanes 0..15 -> contiguous 256B
      bf16x8 v00 = {}, v01 = {}, v10 = {}, v11 = {};
      if (vy0 && vx0) v00 = *(const bf16x8*)(p00 + cc);
      if (vy0 && vx1) v01 = *(const bf16x8*)(p00 + CH + cc);
      if (vy1 && vx0) v10 = *(const bf16x8*)(p00 + WW * CH + cc);
      if (vy1 && vx1) v11 = *(const bf16x8*)(p00 + WW * CH + CH + cc);
      bf16x8 o;
#pragma unroll
      for (int i = 0; i < 8; ++i)
        o[i] = (bf16)(w00 * (float)v00[i] + w01 * (float)v01[i] +
                      w10 * (float)v10[i] + w11 * (float)v11[i]);
      *(bf16x8*)(dst + tap * 256 + cc) = o;
    }
  }
}

// ---------------- 64xTN GEMM: A via dbuf gll16 (counted vmcnt), B direct -----
// L2->reg with 1-step register prefetch (bvbuf[kt&1], static under unroll-2).
// MODE 0: A linear k-major [m][KT].  MODE 1: A implicit im2col from NHWC bf16.
// EPI 1: bf16 store [m][256] + fused BN stats.  EPI 0: atomic 18-col offset epi.
// SWZ 1: flat 784-block grid, XCD-chunked, n-fastest.
template <int MODE, int EPI, int SWZ, int TN, int KS>
__global__ __launch_bounds__(256, 3) void gemm_k(
    const bf16* __restrict__ Asrc, const bf16* __restrict__ Bt,
    const bf16* __restrict__ zp, bf16* __restrict__ outb,
    float* __restrict__ sS, float* __restrict__ sQ,
    float* __restrict__ offout, const int dil, const int pad) {
  constexpr int NF = TN / 32;  // n-frags per wave
  __shared__ __align__(16) bf16 Ab[2][4096];  // 16 KB total
  const int tid = threadIdx.x;
  int n0, m0;
  if (SWZ) {
    const int gid = blockIdx.x;  // 784 = 8 XCDs x 98
    const int swz = (gid & 7) * 98 + (gid >> 3);
    n0 = (swz & 3) * 64;
    m0 = (swz >> 2) * 64;
  } else {
    n0 = blockIdx.x * TN;
    m0 = blockIdx.y * 64;
  }
  const int kbase = blockIdx.z * KS * 64;
  const int lane = tid & 63, wv = tid >> 6;
  const int wrM = wv >> 1, wcN = wv & 1;
  const int fr = lane & 15, kg = lane >> 4;
  const int srow = tid >> 3, cpos = tid & 7;
  const int sxor = (cpos ^ (srow & 7)) * 8;  // source-side swizzle (involution)

  int bb[2], hh[2], wwv[2];
  const bf16* aptr[2];
  if (MODE == 1) {
#pragma unroll
    for (int pa = 0; pa < 2; ++pa) {
      const int m = m0 + pa * 32 + srow;
      bb[pa] = m / HW;
      const int hw = m - bb[pa] * HW;
      hh[pa] = hw / WW;
      wwv[pa] = hw - hh[pa] * WW;
    }
  } else {
#pragma unroll
    for (int pa = 0; pa < 2; ++pa)
      aptr[pa] = Asrc + (size_t)(m0 + pa * 32 + srow) * KT + kbase + sxor;
  }
  // B fragment pointers: lane-contiguous 16B, L2-resident panel
  const bf16* bfp[NF];
#pragma unroll
  for (int nf = 0; nf < NF; ++nf)
    bfp[nf] = Bt + (size_t)(n0 + wcN * (NF * 16) + nf * 16 + fr) * KT + kbase +
              kg * 8;

  f32x4 acc[2][NF] = {};
  bf16x8 bvbuf[2][NF][2];

  auto STAGEA = [&](int kt, int buf) {  // 2 gll16 per thread
    const int kk = kbase + kt * 64;
#pragma unroll
    for (int pa = 0; pa < 2; ++pa) {
      const bf16* as;
      if (MODE == 0) {
        as = aptr[pa] + kt * 64;
      } else {
        const int tap = kk >> 8, coff = kk & 255;
        const int ky = tap / 3, kx = tap - ky * 3;
        const int y = hh[pa] + ky * dil - pad, xx = wwv[pa] + kx * dil - pad;
        const bool ok = ((unsigned)y < HH) && ((unsigned)xx < WW);
        as = ok ? Asrc + ((size_t)(bb[pa] * HW + y * WW + xx) * CH + coff + sxor)
                : zp + sxor;
      }
      gll16(as, &Ab[buf][(pa * 32 + srow) * 64 + cpos * 8]);
    }
  };

  auto LOADB = [&](int kt, int p) {  // 2*NF global 16B loads -> regs
#pragma unroll
    for (int nf = 0; nf < NF; ++nf)
#pragma unroll
      for (int kh = 0; kh < 2; ++kh)
        bvbuf[p][nf][kh] = *(const bf16x8*)(bfp[nf] + kt * 64 + kh * 32);
  };

  auto COMPUTE = [&](int buf, int p) {
#pragma unroll
    for (int kh = 0; kh < 2; ++kh) {
      bf16x8 af[2];
#pragma unroll
      for (int mf = 0; mf < 2; ++mf) {
        const int row = wrM * 32 + mf * 16 + fr;
        const int g = (kh * 4 + kg) ^ (row & 7);
        af[mf] = *(const bf16x8*)&Ab[buf][row * 64 + g * 8];
      }
#pragma unroll
      for (int mf = 0; mf < 2; ++mf)
#pragma unroll
        for (int nf = 0; nf < NF; ++nf)
          acc[mf][nf] = __builtin_amdgcn_mfma_f32_16x16x32_bf16(
              af[mf], bvbuf[p][nf][kh], acc[mf][nf], 0, 0, 0);
    }
  };

  // prologue: B(0) oldest, then A(0), A(1) -> steady wait vmcnt(2) leaves only
  // the next A-batch in flight; B(kt)+A(kt) guaranteed landed.
  LOADB(0, 0);
  STAGEA(0, 0);
  STAGEA(1, 1);
#pragma unroll 2
  for (int kt = 0; kt < KS; ++kt) {
    if (kt + 1 < KS) waitvm<2>();
    else waitvm<0>();
    __builtin_amdgcn_s_barrier();
    __builtin_amdgcn_sched_barrier(0);
    if (kt + 1 < KS) LOADB(kt + 1, (kt + 1) & 1);
    COMPUTE(kt & 1, kt & 1);
    __builtin_amdgcn_sched_barrier(0);
    __builtin_amdgcn_s_barrier();
    if (kt + 2 < KS) STAGEA(kt + 2, kt & 1);
  }

  if constexpr (EPI == 1) {
    // direct bf16 store
#pragma unroll
    for (int mf = 0; mf < 2; ++mf) {
      const int rr = m0 + wrM * 32 + mf * 16 + kg * 4;
#pragma unroll
      for (int nf = 0; nf < NF; ++nf) {
        const int col = n0 + wcN * (NF * 16) + nf * 16 + fr;
#pragma unroll
        for (int r = 0; r < 4; ++r)
          outb[(size_t)(rr + r) * CH + col] = (bf16)acc[mf][nf][r];
      }
    }
    // fused BN stats: per-thread partial -> kg-shuffle -> LDS -> global atomics
    float ps[NF], pq[NF];
#pragma unroll
    for (int nf = 0; nf < NF; ++nf) {
      float s = 0.f, q = 0.f;
#pragma unroll
      for (int mf = 0; mf < 2; ++mf)
#pragma unroll
        for (int r = 0; r < 4; ++r) {
          const float v = acc[mf][nf][r];
          s += v;
          q += v * v;
        }
      s += __shfl_xor(s, 16);
      s += __shfl_xor(s, 32);
      q += __shfl_xor(q, 16);
      q += __shfl_xor(q, 32);
      ps[nf] = s;
      pq[nf] = q;
    }
    float* red = (float*)&Ab[0][0];  // scratch (K-loop done)
    if (tid < 128) red[tid] = 0.f;
    __syncthreads();
    if (kg == 0) {
#pragma unroll
      for (int nf = 0; nf < NF; ++nf) {
        const int cb = wcN * (NF * 16) + nf * 16 + fr;
        atomicAdd(&red[cb], ps[nf]);
        atomicAdd(&red[64 + cb], pq[nf]);
      }
    }
    __syncthreads();
    if (tid < 64) {
      atomicAdd(&sS[n0 + tid], red[tid]);
      atomicAdd(&sQ[n0 + tid], red[64 + tid]);
    }
  } else {
    // split-K offset epilogue
#pragma unroll
    for (int mf = 0; mf < 2; ++mf) {
      const int rr = m0 + wrM * 32 + mf * 16 + kg * 4;
#pragma unroll
      for (int nf = 0; nf < NF; ++nf) {
        const int col = n0 + wcN * (NF * 16) + nf * 16 + fr;
        if (col < 18) {
#pragma unroll
          for (int r = 0; r < 4; ++r)
            atomicAdd(&offout[(size_t)(rr + r) * 18 + col], acc[mf][nf][r]);
        }
      }
    }
  }
}

// ---------------- act = bf16(relu(bn1(in))), affine folded from s/sq ---------
__global__ __launch_bounds__(256) void a1_kb(const bf16* __restrict__ in,
                                             const float* __restrict__ s,
                                             const float* __restrict__ sq,
                                             const float* __restrict__ g,
                                             const float* __restrict__ be,
                                             bf16* __restrict__ out) {
  const size_t idx = (size_t)(blockIdx.x * 256 + threadIdx.x) * 8;
  const int c0 = (int)(idx & 255);
  const float inv = 1.f / (float)MM;
  bf16x8 v = *(const bf16x8*)&in[idx];
  bf16x8 o;
#pragma unroll
  for (int i = 0; i < 8; ++i) {
    const int c = c0 + i;
    const float mean = s[c] * inv;
    const float var = sq[c] * inv - mean * mean;
    const float sc = g[c] * rsqrtf(var + 1e-5f);
    const float bi = be[c] - mean * sc;
    float r = (float)v[i] * sc + bi;
    o[i] = (bf16)(r > 0.f ? r : 0.f);
  }
  *(bf16x8*)&out[idx] = o;
}

// ---------------- out = relu(bn2(o2) + x), bf16 NHWC -> f32 NCHW -------------
__global__ __launch_bounds__(256) void final_kb(const bf16* __restrict__ o2,
                                                const float* __restrict__ x,
                                                const float* __restrict__ s,
                                                const float* __restrict__ sq,
                                                const float* __restrict__ g,
                                                const float* __restrict__ be,
                                                float* __restrict__ out) {
  __shared__ float t[32][33];
  const int b = blockIdx.z, hw0 = blockIdx.x * 32, o0 = blockIdx.y * 32;
  const int tid = threadIdx.x;
  {
    const int hwl = tid >> 3, ol = (tid & 7) * 4;
    bf16x4 v = *(const bf16x4*)&o2[(size_t)(b * HW + hw0 + hwl) * CH + o0 + ol];
#pragma unroll
    for (int i = 0; i < 4; ++i) t[ol + i][hwl] = (float)v[i];
  }
  __syncthreads();
  const int ol = tid >> 3, hwl = (tid & 7) * 4;
  const int ch = o0 + ol;
  const float inv = 1.f / (float)MM;
  const float mean = s[ch] * inv;
  const float var = sq[ch] * inv - mean * mean;
  const float sc = g[ch] * rsqrtf(var + 1e-5f);
  const float bb = be[ch] - mean * sc;
  const size_t xi = (size_t)(b * CH + ch) * HW + hw0 + hwl;
  f32x4 xv = *(const f32x4*)&x[xi];
  f32x4 r;
#pragma unroll
  for (int i = 0; i < 4; ++i) {
    float v = t[ol][hwl + i] * sc + bb + xv[i];
    r[i] = v > 0.f ? v : 0.f;
  }
  *(f32x4*)&out[xi] = r;
}

// ---------------- workspace layout (bytes) ----------------
#define WS_XN 0ULL            // xn NHWC bf16:        6,422,528
#define WS_W1T 6422528ULL     // w1t bf16:            1,179,648
#define WS_W2T 7602176ULL     // w2t bf16:            1,179,648
#define WS_WOF 8781824ULL     // wof bf16 pad64:        294,912
#define WS_OFFB 9076736ULL    // offb f32 [m][18]:      903,168
#define WS_A1 9979904ULL      // A1 bf16 [m][2304]:  57,802,752
#define WS_O1 67782656ULL     // out1 bf16 NHWC:      6,422,528
#define WS_ACT 74205184ULL    // act bf16 NHWC:       6,422,528
#define WS_O2 80627712ULL     // out2 bf16 NHWC:      6,422,528
#define WS_ZP 87050240ULL     // zero page:               4,096
#define WS_STAT 87054336ULL   // s1,sq1,s2,sq2:           4,096
// total: 87,058,432

extern "C" void kernel_launch(void* const* d_in, const int* in_sizes, int n_in,
                              void* d_out, int out_size, void* d_ws, size_t ws_size,
                              hipStream_t stream) {
  const float* x = (const float*)d_in[0];
  const float* w_off = (const float*)d_in[1];
  const float* b_off = (const float*)d_in[2];
  const float* w1 = (const float*)d_in[3];
  const float* g1 = (const float*)d_in[4];
  const float* be1 = (const float*)d_in[5];
  const float* w2 = (const float*)d_in[6];
  const float* g2 = (const float*)d_in[7];
  const float* be2 = (const float*)d_in[8];
  float* out = (float*)d_out;
  char* ws = (char*)d_ws;

  bf16* xn = (bf16*)(ws + WS_XN);
  bf16* w1t = (bf16*)(ws + WS_W1T);
  bf16* w2t = (bf16*)(ws + WS_W2T);
  bf16* wof = (bf16*)(ws + WS_WOF);
  float* offb = (float*)(ws + WS_OFFB);
  bf16* A1 = (bf16*)(ws + WS_A1);
  bf16* o1 = (bf16*)(ws + WS_O1);
  bf16* act = (bf16*)(ws + WS_ACT);
  bf16* o2 = (bf16*)(ws + WS_O2);
  bf16* zp = (bf16*)(ws + WS_ZP);
  float* s1 = (float*)(ws + WS_STAT);
  float* sq1 = (float*)(ws + WS_STAT + 1024);
  float* s2 = (float*)(ws + WS_STAT + 2048);
  float* sq2 = (float*)(ws + WS_STAT + 3072);

  hipMemsetAsync(ws + WS_ZP, 0, 8192, stream);      // zp + stats
  hipMemsetAsync(ws + WS_OFFB, 0, 903168, stream);  // offset split-K accum

  nchw2nhwc_k<<<dim3(98, 8, 4), 256, 0, stream>>>(x, xn);
  reorder_all_k<<<5184, 256, 0, stream>>>(w1, w2, w_off, w1t, w2t, wof);

  // offset conv: implicit im2col (dil2,pad2), TN=32, split-K=4 -> offb
  gemm_k<1, 0, 0, 32, 9><<<dim3(1, 196, 4), 256, 0, stream>>>(
      xn, wof, zp, nullptr, nullptr, nullptr, offb, 2, 2);

  // deform sample -> A1
  build_deform_k<<<784, 256, 0, stream>>>(xn, offb, b_off, A1);

  // deform GEMM: linear A1, full-K, XCD-swizzled -> o1 bf16 (+stats)
  gemm_k<0, 1, 1, 64, 36><<<dim3(784), 256, 0, stream>>>(
      A1, w1t, zp, o1, s1, sq1, nullptr, 0, 0);
  a1_kb<<<1568, 256, 0, stream>>>(o1, s1, sq1, g1, be1, act);

  // conv2: implicit im2col (dil1,pad1), full-K, XCD-swizzled -> o2 bf16 (+stats)
  gemm_k<1, 1, 1, 64, 36><<<dim3(784), 256, 0, stream>>>(
      act, w2t, zp, o2, s2, sq2, nullptr, 1, 1);

  final_kb<<<dim3(98, 8, 4), 256, 0, stream>>>(o2, x, s2, sq2, g2, be2, out);
}

// Round 12
// 203.987 us; speedup vs baseline: 1.4727x; 1.4727x over previous
//
#include <hip/hip_runtime.h>

typedef __bf16 bf16;
typedef bf16 bf16x4 __attribute__((ext_vector_type(4)));
typedef bf16 bf16x8 __attribute__((ext_vector_type(8)));
typedef float f32x4 __attribute__((ext_vector_type(4)));

#define CH 256
#define HH 56
#define WW 56
#define HW 3136
#define MM 12544
#define KT 2304

__device__ __forceinline__ void gll16(const bf16* g, bf16* l) {
  __builtin_amdgcn_global_load_lds(
      (const __attribute__((address_space(1))) void*)g,
      (__attribute__((address_space(3))) void*)l, 16, 0, 0);
}

template <int N>
__device__ __forceinline__ void waitvm() {
  if constexpr (N == 0) asm volatile("s_waitcnt vmcnt(0)" ::: "memory");
  else if constexpr (N == 3) asm volatile("s_waitcnt vmcnt(3)" ::: "memory");
  else if constexpr (N == 4) asm volatile("s_waitcnt vmcnt(4)" ::: "memory");
}

// ---------------- NCHW fp32 -> NHWC bf16 ----------------
__global__ __launch_bounds__(256) void nchw2nhwc_k(const float* __restrict__ x,
                                                   bf16* __restrict__ o) {
  __shared__ float t[32][33];
  const int b = blockIdx.z, hw0 = blockIdx.x * 32, c0 = blockIdx.y * 32;
  const int tid = threadIdx.x;
  {
    const int cl = tid >> 3, hwl = (tid & 7) * 4;
    f32x4 v = *(const f32x4*)&x[(size_t)(b * CH + c0 + cl) * HW + hw0 + hwl];
#pragma unroll
    for (int i = 0; i < 4; ++i) t[cl][hwl + i] = v[i];
  }
  __syncthreads();
  const int hwl = tid >> 3, cl = (tid & 7) * 4;
  bf16x4 ov;
#pragma unroll
  for (int i = 0; i < 4; ++i) ov[i] = (bf16)t[cl + i][hwl];
  *(bf16x4*)&o[(size_t)(b * HW + hw0 + hwl) * CH + c0 + cl] = ov;
}

// ---------------- all weight reorders in one launch ----------------
__global__ void reorder_all_k(const float* __restrict__ w1,
                              const float* __restrict__ w2,
                              const float* __restrict__ woff,
                              bf16* __restrict__ w1t, bf16* __restrict__ w2t,
                              bf16* __restrict__ wof) {
  const int gid = blockIdx.x;
  if (gid < 4608) {
    const int idx = gid * 256 + threadIdx.x;
    const float* in = (gid < 2304) ? w1 : w2;
    bf16* out = (gid < 2304) ? w1t : w2t;
    const int li = (gid < 2304) ? idx : idx - 2304 * 256;
    const int o = li / KT, r = li - o * KT;
    const int k = r >> 8, c = r & 255;
    out[li] = (bf16)in[(size_t)(o * CH + c) * 9 + k];
  } else {
    const int li = (gid - 4608) * 256 + threadIdx.x;
    const int o = li / KT, r = li - o * KT;
    const int k = r >> 8, c = r & 255;
    wof[li] = (bf16)((o < 18) ? woff[(size_t)(o * CH + c) * 9 + k] : 0.f);
  }
}

// ---------------- deform sample: 16 rows/block, contiguous-line writes -------
__global__ __launch_bounds__(256) void build_deform_k(
    const bf16* __restrict__ xn, const float* __restrict__ offb,
    const float* __restrict__ boff, bf16* __restrict__ A1) {
  const int tid = threadIdx.x;
  const int m = blockIdx.x * 16 + (tid >> 4);
  const int l15 = tid & 15;
  const int b = m / HW, hw = m - b * HW;
  const int h = hw / WW, w = hw - h * WW;
  const float* orow = offb + m * 18;
  const bf16* xb = xn + (size_t)b * HW * CH;
  bf16* dst = A1 + (size_t)m * KT;
  for (int tap = 0; tap < 9; ++tap) {
    const int ky = tap / 3, kx = tap - ky * 3;
    const float dy = orow[2 * tap] + boff[2 * tap];
    const float dx = orow[2 * tap + 1] + boff[2 * tap + 1];
    const float py = (float)(h + ky * 2 - 2) + dy;
    const float px = (float)(w + kx * 2 - 2) + dx;
    const float y0f = floorf(py), x0f = floorf(px);
    const int y0 = (int)y0f, x0 = (int)x0f;
    const float wy = py - y0f, wx = px - x0f;
    const float w00 = (1.f - wy) * (1.f - wx), w01 = (1.f - wy) * wx;
    const float w10 = wy * (1.f - wx), w11 = wy * wx;
    const bool vy0 = (unsigned)y0 < HH, vy1 = (unsigned)(y0 + 1) < HH;
    const bool vx0 = (unsigned)x0 < WW, vx1 = (unsigned)(x0 + 1) < WW;
    const bf16* p00 = xb + (long long)(y0 * WW + x0) * CH;
#pragma unroll
    for (int j = 0; j < 2; ++j) {
      const int cc = j * 128 + l15 * 8;  // lanes 0..15 -> contiguous 256B
      bf16x8 v00 = {}, v01 = {}, v10 = {}, v11 = {};
      if (vy0 && vx0) v00 = *(const bf16x8*)(p00 + cc);
      if (vy0 && vx1) v01 = *(const bf16x8*)(p00 + CH + cc);
      if (vy1 && vx0) v10 = *(const bf16x8*)(p00 + WW * CH + cc);
      if (vy1 && vx1) v11 = *(const bf16x8*)(p00 + WW * CH + CH + cc);
      bf16x8 o;
#pragma unroll
      for (int i = 0; i < 8; ++i)
        o[i] = (bf16)(w00 * (float)v00[i] + w01 * (float)v01[i] +
                      w10 * (float)v10[i] + w11 * (float)v11[i]);
      *(bf16x8*)(dst + tap * 256 + cc) = o;
    }
  }
}

// ---------------- 64xTN GEMM tile, depth-2 dbuf gll16 + counted vmcnt --------
// (r10-proven structure. Lesson r11: B MUST go через LDS — direct per-lane
// fragment loads from k-major B are a 16-cache-line gather and serialize.)
// MODE 0: A linear k-major [m][KT].  MODE 1: A implicit im2col from NHWC bf16.
// EPI 1: bf16 store [m][256] + fused BN stats.  EPI 0: atomic 18-col offset epi.
// SWZ 1: flat 784-block grid, XCD-chunked, n-fastest.
template <int MODE, int EPI, int SWZ, int TN, int KS>
__global__ __launch_bounds__(256, 3) void gemm_k(
    const bf16* __restrict__ Asrc, const bf16* __restrict__ Bt,
    const bf16* __restrict__ zp, bf16* __restrict__ outb,
    float* __restrict__ sS, float* __restrict__ sQ,
    float* __restrict__ offout, const int dil, const int pad) {
  constexpr int PB = TN / 32;  // B rows staged per thread
  constexpr int NF = TN / 32;  // n-frags per wave
  constexpr int SL = 2 + PB;   // gll16 per thread per STAGE
  __shared__ __align__(16) bf16 Ab[2][4096];
  __shared__ __align__(16) bf16 Bb[2][TN * 64];
  const int tid = threadIdx.x;
  int n0, m0;
  if (SWZ) {
    const int gid = blockIdx.x;  // 784 = 8 XCDs x 98
    const int swz = (gid & 7) * 98 + (gid >> 3);
    n0 = (swz & 3) * 64;
    m0 = (swz >> 2) * 64;
  } else {
    n0 = blockIdx.x * TN;
    m0 = blockIdx.y * 64;
  }
  const int kbase = blockIdx.z * KS * 64;
  const int lane = tid & 63, wv = tid >> 6;
  const int wrM = wv >> 1, wcN = wv & 1;
  const int fr = lane & 15, kg = lane >> 4;
  const int srow = tid >> 3, cpos = tid & 7;
  const int sxor = (cpos ^ (srow & 7)) * 8;  // source-side swizzle (involution)

  int bb[2], hh[2], wwv[2];
  const bf16* aptr[2];
  if (MODE == 1) {
#pragma unroll
    for (int pa = 0; pa < 2; ++pa) {
      const int m = m0 + pa * 32 + srow;
      bb[pa] = m / HW;
      const int hw = m - bb[pa] * HW;
      hh[pa] = hw / WW;
      wwv[pa] = hw - hh[pa] * WW;
    }
  } else {
#pragma unroll
    for (int pa = 0; pa < 2; ++pa)
      aptr[pa] = Asrc + (size_t)(m0 + pa * 32 + srow) * KT + kbase + sxor;
  }
  const bf16* bptr[PB];
#pragma unroll
  for (int pb = 0; pb < PB; ++pb)
    bptr[pb] = Bt + (size_t)(n0 + pb * 32 + srow) * KT + kbase + sxor;

  f32x4 acc[2][NF] = {};

  auto STAGE = [&](int kt, int buf) {  // SL gll16 per thread
    const int kk = kbase + kt * 64;
#pragma unroll
    for (int pa = 0; pa < 2; ++pa) {
      const bf16* as;
      if (MODE == 0) {
        as = aptr[pa] + kt * 64;
      } else {
        const int tap = kk >> 8, coff = kk & 255;
        const int ky = tap / 3, kx = tap - ky * 3;
        const int y = hh[pa] + ky * dil - pad, xx = wwv[pa] + kx * dil - pad;
        const bool ok = ((unsigned)y < HH) && ((unsigned)xx < WW);
        as = ok ? Asrc + ((size_t)(bb[pa] * HW + y * WW + xx) * CH + coff + sxor)
                : zp + sxor;
      }
      gll16(as, &Ab[buf][(pa * 32 + srow) * 64 + cpos * 8]);
    }
#pragma unroll
    for (int pb = 0; pb < PB; ++pb)
      gll16(bptr[pb] + kt * 64, &Bb[buf][(pb * 32 + srow) * 64 + cpos * 8]);
  };

  auto COMPUTE = [&](int buf) {
#pragma unroll
    for (int kh = 0; kh < 2; ++kh) {
      bf16x8 af[2], bv[NF];
#pragma unroll
      for (int mf = 0; mf < 2; ++mf) {
        const int row = wrM * 32 + mf * 16 + fr;
        const int g = (kh * 4 + kg) ^ (row & 7);
        af[mf] = *(const bf16x8*)&Ab[buf][row * 64 + g * 8];
      }
#pragma unroll
      for (int nf = 0; nf < NF; ++nf) {
        const int row = wcN * (NF * 16) + nf * 16 + fr;
        const int g = (kh * 4 + kg) ^ (row & 7);
        bv[nf] = *(const bf16x8*)&Bb[buf][row * 64 + g * 8];
      }
#pragma unroll
      for (int mf = 0; mf < 2; ++mf)
#pragma unroll
        for (int nf = 0; nf < NF; ++nf)
          acc[mf][nf] = __builtin_amdgcn_mfma_f32_16x16x32_bf16(af[mf], bv[nf],
                                                                acc[mf][nf], 0, 0, 0);
    }
  };

  // depth-2 pipeline, counted vmcnt: batch for tile k issued at bottom of
  // iter k-2, waited at top of iter k.
  STAGE(0, 0);
  STAGE(1, 1);
  int buf = 0;
  for (int kt = 0; kt < KS; ++kt) {
    if (kt + 1 < KS) waitvm<SL>();
    else waitvm<0>();
    __builtin_amdgcn_s_barrier();
    __builtin_amdgcn_sched_barrier(0);
    COMPUTE(buf);
    __builtin_amdgcn_sched_barrier(0);
    __builtin_amdgcn_s_barrier();
    if (kt + 2 < KS) STAGE(kt + 2, buf);
    buf ^= 1;
  }

  if constexpr (EPI == 1) {
    // direct bf16 store
#pragma unroll
    for (int mf = 0; mf < 2; ++mf) {
      const int rr = m0 + wrM * 32 + mf * 16 + kg * 4;
#pragma unroll
      for (int nf = 0; nf < NF; ++nf) {
        const int col = n0 + wcN * (NF * 16) + nf * 16 + fr;
#pragma unroll
        for (int r = 0; r < 4; ++r)
          outb[(size_t)(rr + r) * CH + col] = (bf16)acc[mf][nf][r];
      }
    }
    // fused BN stats: per-thread partial -> kg-shuffle -> LDS -> global atomics
    float ps[NF], pq[NF];
#pragma unroll
    for (int nf = 0; nf < NF; ++nf) {
      float s = 0.f, q = 0.f;
#pragma unroll
      for (int mf = 0; mf < 2; ++mf)
#pragma unroll
        for (int r = 0; r < 4; ++r) {
          const float v = acc[mf][nf][r];
          s += v;
          q += v * v;
        }
      s += __shfl_xor(s, 16);
      s += __shfl_xor(s, 32);
      q += __shfl_xor(q, 16);
      q += __shfl_xor(q, 32);
      ps[nf] = s;
      pq[nf] = q;
    }
    float* red = (float*)&Ab[0][0];  // scratch (K-loop done)
    if (tid < 128) red[tid] = 0.f;
    __syncthreads();
    if (kg == 0) {
#pragma unroll
      for (int nf = 0; nf < NF; ++nf) {
        const int cb = wcN * (NF * 16) + nf * 16 + fr;
        atomicAdd(&red[cb], ps[nf]);
        atomicAdd(&red[64 + cb], pq[nf]);
      }
    }
    __syncthreads();
    if (tid < 64) {
      atomicAdd(&sS[n0 + tid], red[tid]);
      atomicAdd(&sQ[n0 + tid], red[64 + tid]);
    }
  } else {
    // split-K offset epilogue
#pragma unroll
    for (int mf = 0; mf < 2; ++mf) {
      const int rr = m0 + wrM * 32 + mf * 16 + kg * 4;
#pragma unroll
      for (int nf = 0; nf < NF; ++nf) {
        const int col = n0 + wcN * (NF * 16) + nf * 16 + fr;
        if (col < 18) {
#pragma unroll
          for (int r = 0; r < 4; ++r)
            atomicAdd(&offout[(size_t)(rr + r) * 18 + col], acc[mf][nf][r]);
        }
      }
    }
  }
}

// ---------------- act = bf16(relu(bn1(in))), affine folded from s/sq ---------
__global__ __launch_bounds__(256) void a1_kb(const bf16* __restrict__ in,
                                             const float* __restrict__ s,
                                             const float* __restrict__ sq,
                                             const float* __restrict__ g,
                                             const float* __restrict__ be,
                                             bf16* __restrict__ out) {
  const size_t idx = (size_t)(blockIdx.x * 256 + threadIdx.x) * 8;
  const int c0 = (int)(idx & 255);
  const float inv = 1.f / (float)MM;
  bf16x8 v = *(const bf16x8*)&in[idx];
  bf16x8 o;
#pragma unroll
  for (int i = 0; i < 8; ++i) {
    const int c = c0 + i;
    const float mean = s[c] * inv;
    const float var = sq[c] * inv - mean * mean;
    const float sc = g[c] * rsqrtf(var + 1e-5f);
    const float bi = be[c] - mean * sc;
    float r = (float)v[i] * sc + bi;
    o[i] = (bf16)(r > 0.f ? r : 0.f);
  }
  *(bf16x8*)&out[idx] = o;
}

// ---------------- out = relu(bn2(o2) + x), bf16 NHWC -> f32 NCHW -------------
__global__ __launch_bounds__(256) void final_kb(const bf16* __restrict__ o2,
                                                const float* __restrict__ x,
                                                const float* __restrict__ s,
                                                const float* __restrict__ sq,
                                                const float* __restrict__ g,
                                                const float* __restrict__ be,
                                                float* __restrict__ out) {
  __shared__ float t[32][33];
  const int b = blockIdx.z, hw0 = blockIdx.x * 32, o0 = blockIdx.y * 32;
  const int tid = threadIdx.x;
  {
    const int hwl = tid >> 3, ol = (tid & 7) * 4;
    bf16x4 v = *(const bf16x4*)&o2[(size_t)(b * HW + hw0 + hwl) * CH + o0 + ol];
#pragma unroll
    for (int i = 0; i < 4; ++i) t[ol + i][hwl] = (float)v[i];
  }
  __syncthreads();
  const int ol = tid >> 3, hwl = (tid & 7) * 4;
  const int ch = o0 + ol;
  const float inv = 1.f / (float)MM;
  const float mean = s[ch] * inv;
  const float var = sq[ch] * inv - mean * mean;
  const float sc = g[ch] * rsqrtf(var + 1e-5f);
  const float bb = be[ch] - mean * sc;
  const size_t xi = (size_t)(b * CH + ch) * HW + hw0 + hwl;
  f32x4 xv = *(const f32x4*)&x[xi];
  f32x4 r;
#pragma unroll
  for (int i = 0; i < 4; ++i) {
    float v = t[ol][hwl + i] * sc + bb + xv[i];
    r[i] = v > 0.f ? v : 0.f;
  }
  *(f32x4*)&out[xi] = r;
}

// ---------------- workspace layout (bytes) ----------------
#define WS_XN 0ULL            // xn NHWC bf16:        6,422,528
#define WS_W1T 6422528ULL     // w1t bf16:            1,179,648
#define WS_W2T 7602176ULL     // w2t bf16:            1,179,648
#define WS_WOF 8781824ULL     // wof bf16 pad64:        294,912
#define WS_OFFB 9076736ULL    // offb f32 [m][18]:      903,168
#define WS_A1 9979904ULL      // A1 bf16 [m][2304]:  57,802,752
#define WS_O1 67782656ULL     // out1 bf16 NHWC:      6,422,528
#define WS_ACT 74205184ULL    // act bf16 NHWC:       6,422,528
#define WS_O2 80627712ULL     // out2 bf16 NHWC:      6,422,528
#define WS_ZP 87050240ULL     // zero page:               4,096
#define WS_STAT 87054336ULL   // s1,sq1,s2,sq2:           4,096
// total: 87,058,432

extern "C" void kernel_launch(void* const* d_in, const int* in_sizes, int n_in,
                              void* d_out, int out_size, void* d_ws, size_t ws_size,
                              hipStream_t stream) {
  const float* x = (const float*)d_in[0];
  const float* w_off = (const float*)d_in[1];
  const float* b_off = (const float*)d_in[2];
  const float* w1 = (const float*)d_in[3];
  const float* g1 = (const float*)d_in[4];
  const float* be1 = (const float*)d_in[5];
  const float* w2 = (const float*)d_in[6];
  const float* g2 = (const float*)d_in[7];
  const float* be2 = (const float*)d_in[8];
  float* out = (float*)d_out;
  char* ws = (char*)d_ws;

  bf16* xn = (bf16*)(ws + WS_XN);
  bf16* w1t = (bf16*)(ws + WS_W1T);
  bf16* w2t = (bf16*)(ws + WS_W2T);
  bf16* wof = (bf16*)(ws + WS_WOF);
  float* offb = (float*)(ws + WS_OFFB);
  bf16* A1 = (bf16*)(ws + WS_A1);
  bf16* o1 = (bf16*)(ws + WS_O1);
  bf16* act = (bf16*)(ws + WS_ACT);
  bf16* o2 = (bf16*)(ws + WS_O2);
  bf16* zp = (bf16*)(ws + WS_ZP);
  float* s1 = (float*)(ws + WS_STAT);
  float* sq1 = (float*)(ws + WS_STAT + 1024);
  float* s2 = (float*)(ws + WS_STAT + 2048);
  float* sq2 = (float*)(ws + WS_STAT + 3072);

  hipMemsetAsync(ws + WS_ZP, 0, 8192, stream);      // zp + stats
  hipMemsetAsync(ws + WS_OFFB, 0, 903168, stream);  // offset split-K accum

  nchw2nhwc_k<<<dim3(98, 8, 4), 256, 0, stream>>>(x, xn);
  reorder_all_k<<<5184, 256, 0, stream>>>(w1, w2, w_off, w1t, w2t, wof);

  // offset conv: implicit im2col (dil2,pad2), TN=32, split-K=4 -> offb
  gemm_k<1, 0, 0, 32, 9><<<dim3(1, 196, 4), 256, 0, stream>>>(
      xn, wof, zp, nullptr, nullptr, nullptr, offb, 2, 2);

  // deform sample -> A1
  build_deform_k<<<784, 256, 0, stream>>>(xn, offb, b_off, A1);

  // deform GEMM: linear A1, full-K, XCD-swizzled -> o1 bf16 (+stats)
  gemm_k<0, 1, 1, 64, 36><<<dim3(784), 256, 0, stream>>>(
      A1, w1t, zp, o1, s1, sq1, nullptr, 0, 0);
  a1_kb<<<1568, 256, 0, stream>>>(o1, s1, sq1, g1, be1, act);

  // conv2: implicit im2col (dil1,pad1), full-K, XCD-swizzled -> o2 bf16 (+stats)
  gemm_k<1, 1, 1, 64, 36><<<dim3(784), 256, 0, stream>>>(
      act, w2t, zp, o2, s2, sq2, nullptr, 1, 1);

  final_kb<<<dim3(98, 8, 4), 256, 0, stream>>>(o2, x, s2, sq2, g2, be2, out);
}

// Round 13
// 197.364 us; speedup vs baseline: 1.5221x; 1.0336x over previous
//
#include <hip/hip_runtime.h>

typedef __bf16 bf16;
typedef bf16 bf16x4 __attribute__((ext_vector_type(4)));
typedef bf16 bf16x8 __attribute__((ext_vector_type(8)));
typedef float f32x4 __attribute__((ext_vector_type(4)));

#define CH 256
#define HH 56
#define WW 56
#define HW 3136
#define MM 12544
#define KT 2304

__device__ __forceinline__ void gll16(const bf16* g, bf16* l) {
  __builtin_amdgcn_global_load_lds(
      (const __attribute__((address_space(1))) void*)g,
      (__attribute__((address_space(3))) void*)l, 16, 0, 0);
}

template <int N>
__device__ __forceinline__ void waitvm() {
  if constexpr (N == 0) asm volatile("s_waitcnt vmcnt(0)" ::: "memory");
  else if constexpr (N == 3) asm volatile("s_waitcnt vmcnt(3)" ::: "memory");
  else if constexpr (N == 4) asm volatile("s_waitcnt vmcnt(4)" ::: "memory");
}

// ---------------- prep: NCHW->NHWC transpose + all weight reorders, 1 launch -
__global__ __launch_bounds__(256) void prep_k(
    const float* __restrict__ x, bf16* __restrict__ xn,
    const float* __restrict__ w1, const float* __restrict__ w2,
    const float* __restrict__ woff, bf16* __restrict__ w1t,
    bf16* __restrict__ w2t, bf16* __restrict__ wof) {
  __shared__ float t[32][33];
  const int gid = blockIdx.x;
  const int tid = threadIdx.x;
  if (gid < 3136) {  // transpose tiles: 98 x 8 x 4
    const int bx = gid % 98, r = gid / 98;
    const int by = r & 7, b = r >> 3;
    const int hw0 = bx * 32, c0 = by * 32;
    {
      const int cl = tid >> 3, hwl = (tid & 7) * 4;
      f32x4 v = *(const f32x4*)&x[(size_t)(b * CH + c0 + cl) * HW + hw0 + hwl];
#pragma unroll
      for (int i = 0; i < 4; ++i) t[cl][hwl + i] = v[i];
    }
    __syncthreads();
    const int hwl = tid >> 3, cl = (tid & 7) * 4;
    bf16x4 ov;
#pragma unroll
    for (int i = 0; i < 4; ++i) ov[i] = (bf16)t[cl + i][hwl];
    *(bf16x4*)&xn[(size_t)(b * HW + hw0 + hwl) * CH + c0 + cl] = ov;
  } else if (gid < 3136 + 4608) {  // w1/w2 reorder
    const int g2 = gid - 3136;
    const int idx = g2 * 256 + tid;
    const float* in = (g2 < 2304) ? w1 : w2;
    bf16* out = (g2 < 2304) ? w1t : w2t;
    const int li = (g2 < 2304) ? idx : idx - 2304 * 256;
    const int o = li / KT, r = li - o * KT;
    const int k = r >> 8, c = r & 255;
    out[li] = (bf16)in[(size_t)(o * CH + c) * 9 + k];
  } else {  // w_off reorder (pad to 64 rows)
    const int li = (gid - 3136 - 4608) * 256 + tid;
    const int o = li / KT, r = li - o * KT;
    const int k = r >> 8, c = r & 255;
    wof[li] = (bf16)((o < 18) ? woff[(size_t)(o * CH + c) * 9 + k] : 0.f);
  }
}

// ---------------- deform sample: 16 rows/block, contiguous-line writes -------
__global__ __launch_bounds__(256) void build_deform_k(
    const bf16* __restrict__ xn, const float* __restrict__ offb,
    const float* __restrict__ boff, bf16* __restrict__ A1) {
  const int tid = threadIdx.x;
  const int m = blockIdx.x * 16 + (tid >> 4);
  const int l15 = tid & 15;
  const int b = m / HW, hw = m - b * HW;
  const int h = hw / WW, w = hw - h * WW;
  const float* orow = offb + m * 18;
  const bf16* xb = xn + (size_t)b * HW * CH;
  bf16* dst = A1 + (size_t)m * KT;
  for (int tap = 0; tap < 9; ++tap) {
    const int ky = tap / 3, kx = tap - ky * 3;
    const float dy = orow[2 * tap] + boff[2 * tap];
    const float dx = orow[2 * tap + 1] + boff[2 * tap + 1];
    const float py = (float)(h + ky * 2 - 2) + dy;
    const float px = (float)(w + kx * 2 - 2) + dx;
    const float y0f = floorf(py), x0f = floorf(px);
    const int y0 = (int)y0f, x0 = (int)x0f;
    const float wy = py - y0f, wx = px - x0f;
    const float w00 = (1.f - wy) * (1.f - wx), w01 = (1.f - wy) * wx;
    const float w10 = wy * (1.f - wx), w11 = wy * wx;
    const bool vy0 = (unsigned)y0 < HH, vy1 = (unsigned)(y0 + 1) < HH;
    const bool vx0 = (unsigned)x0 < WW, vx1 = (unsigned)(x0 + 1) < WW;
    const bf16* p00 = xb + (long long)(y0 * WW + x0) * CH;
#pragma unroll
    for (int j = 0; j < 2; ++j) {
      const int cc = j * 128 + l15 * 8;  // lanes 0..15 -> contiguous 256B
      bf16x8 v00 = {}, v01 = {}, v10 = {}, v11 = {};
      if (vy0 && vx0) v00 = *(const bf16x8*)(p00 + cc);
      if (vy0 && vx1) v01 = *(const bf16x8*)(p00 + CH + cc);
      if (vy1 && vx0) v10 = *(const bf16x8*)(p00 + WW * CH + cc);
      if (vy1 && vx1) v11 = *(const bf16x8*)(p00 + WW * CH + CH + cc);
      bf16x8 o;
#pragma unroll
      for (int i = 0; i < 8; ++i)
        o[i] = (bf16)(w00 * (float)v00[i] + w01 * (float)v01[i] +
                      w10 * (float)v10[i] + w11 * (float)v11[i]);
      *(bf16x8*)(dst + tap * 256 + cc) = o;
    }
  }
}

// ---------------- 64xTN GEMM tile, depth-2 dbuf gll16 + counted vmcnt --------
// (r10-proven. r11 lesson: B must go through LDS — direct per-lane fragment
// loads from k-major B are a 16-cache-line gather.)  + T5 setprio probe.
template <int MODE, int EPI, int SWZ, int TN, int KS>
__global__ __launch_bounds__(256, 3) void gemm_k(
    const bf16* __restrict__ Asrc, const bf16* __restrict__ Bt,
    const bf16* __restrict__ zp, bf16* __restrict__ outb,
    float* __restrict__ sS, float* __restrict__ sQ,
    float* __restrict__ offout, const int dil, const int pad) {
  constexpr int PB = TN / 32;  // B rows staged per thread
  constexpr int NF = TN / 32;  // n-frags per wave
  constexpr int SL = 2 + PB;   // gll16 per thread per STAGE
  __shared__ __align__(16) bf16 Ab[2][4096];
  __shared__ __align__(16) bf16 Bb[2][TN * 64];
  const int tid = threadIdx.x;
  int n0, m0;
  if (SWZ) {
    const int gid = blockIdx.x;  // 784 = 8 XCDs x 98
    const int swz = (gid & 7) * 98 + (gid >> 3);
    n0 = (swz & 3) * 64;
    m0 = (swz >> 2) * 64;
  } else {
    n0 = blockIdx.x * TN;
    m0 = blockIdx.y * 64;
  }
  const int kbase = blockIdx.z * KS * 64;
  const int lane = tid & 63, wv = tid >> 6;
  const int wrM = wv >> 1, wcN = wv & 1;
  const int fr = lane & 15, kg = lane >> 4;
  const int srow = tid >> 3, cpos = tid & 7;
  const int sxor = (cpos ^ (srow & 7)) * 8;  // source-side swizzle (involution)

  int bb[2], hh[2], wwv[2];
  const bf16* aptr[2];
  if (MODE == 1) {
#pragma unroll
    for (int pa = 0; pa < 2; ++pa) {
      const int m = m0 + pa * 32 + srow;
      bb[pa] = m / HW;
      const int hw = m - bb[pa] * HW;
      hh[pa] = hw / WW;
      wwv[pa] = hw - hh[pa] * WW;
    }
  } else {
#pragma unroll
    for (int pa = 0; pa < 2; ++pa)
      aptr[pa] = Asrc + (size_t)(m0 + pa * 32 + srow) * KT + kbase + sxor;
  }
  const bf16* bptr[PB];
#pragma unroll
  for (int pb = 0; pb < PB; ++pb)
    bptr[pb] = Bt + (size_t)(n0 + pb * 32 + srow) * KT + kbase + sxor;

  f32x4 acc[2][NF] = {};

  auto STAGE = [&](int kt, int buf) {  // SL gll16 per thread
    const int kk = kbase + kt * 64;
#pragma unroll
    for (int pa = 0; pa < 2; ++pa) {
      const bf16* as;
      if (MODE == 0) {
        as = aptr[pa] + kt * 64;
      } else {
        const int tap = kk >> 8, coff = kk & 255;
        const int ky = tap / 3, kx = tap - ky * 3;
        const int y = hh[pa] + ky * dil - pad, xx = wwv[pa] + kx * dil - pad;
        const bool ok = ((unsigned)y < HH) && ((unsigned)xx < WW);
        as = ok ? Asrc + ((size_t)(bb[pa] * HW + y * WW + xx) * CH + coff + sxor)
                : zp + sxor;
      }
      gll16(as, &Ab[buf][(pa * 32 + srow) * 64 + cpos * 8]);
    }
#pragma unroll
    for (int pb = 0; pb < PB; ++pb)
      gll16(bptr[pb] + kt * 64, &Bb[buf][(pb * 32 + srow) * 64 + cpos * 8]);
  };

  auto COMPUTE = [&](int buf) {
#pragma unroll
    for (int kh = 0; kh < 2; ++kh) {
      bf16x8 af[2], bv[NF];
#pragma unroll
      for (int mf = 0; mf < 2; ++mf) {
        const int row = wrM * 32 + mf * 16 + fr;
        const int g = (kh * 4 + kg) ^ (row & 7);
        af[mf] = *(const bf16x8*)&Ab[buf][row * 64 + g * 8];
      }
#pragma unroll
      for (int nf = 0; nf < NF; ++nf) {
        const int row = wcN * (NF * 16) + nf * 16 + fr;
        const int g = (kh * 4 + kg) ^ (row & 7);
        bv[nf] = *(const bf16x8*)&Bb[buf][row * 64 + g * 8];
      }
      __builtin_amdgcn_s_setprio(1);  // T5: favor MFMA-phase wave on CU sched
#pragma unroll
      for (int mf = 0; mf < 2; ++mf)
#pragma unroll
        for (int nf = 0; nf < NF; ++nf)
          acc[mf][nf] = __builtin_amdgcn_mfma_f32_16x16x32_bf16(af[mf], bv[nf],
                                                                acc[mf][nf], 0, 0, 0);
      __builtin_amdgcn_s_setprio(0);
    }
  };

  // depth-2 pipeline, counted vmcnt: batch for tile k issued at bottom of
  // iter k-2, waited at top of iter k.
  STAGE(0, 0);
  STAGE(1, 1);
  int buf = 0;
  for (int kt = 0; kt < KS; ++kt) {
    if (kt + 1 < KS) waitvm<SL>();
    else waitvm<0>();
    __builtin_amdgcn_s_barrier();
    __builtin_amdgcn_sched_barrier(0);
    COMPUTE(buf);
    __builtin_amdgcn_sched_barrier(0);
    __builtin_amdgcn_s_barrier();
    if (kt + 2 < KS) STAGE(kt + 2, buf);
    buf ^= 1;
  }

  if constexpr (EPI == 1) {
    // direct bf16 store
#pragma unroll
    for (int mf = 0; mf < 2; ++mf) {
      const int rr = m0 + wrM * 32 + mf * 16 + kg * 4;
#pragma unroll
      for (int nf = 0; nf < NF; ++nf) {
        const int col = n0 + wcN * (NF * 16) + nf * 16 + fr;
#pragma unroll
        for (int r = 0; r < 4; ++r)
          outb[(size_t)(rr + r) * CH + col] = (bf16)acc[mf][nf][r];
      }
    }
    // fused BN stats: per-thread partial -> kg-shuffle -> LDS -> global atomics
    float ps[NF], pq[NF];
#pragma unroll
    for (int nf = 0; nf < NF; ++nf) {
      float s = 0.f, q = 0.f;
#pragma unroll
      for (int mf = 0; mf < 2; ++mf)
#pragma unroll
        for (int r = 0; r < 4; ++r) {
          const float v = acc[mf][nf][r];
          s += v;
          q += v * v;
        }
      s += __shfl_xor(s, 16);
      s += __shfl_xor(s, 32);
      q += __shfl_xor(q, 16);
      q += __shfl_xor(q, 32);
      ps[nf] = s;
      pq[nf] = q;
    }
    float* red = (float*)&Ab[0][0];  // scratch (K-loop done)
    if (tid < 128) red[tid] = 0.f;
    __syncthreads();
    if (kg == 0) {
#pragma unroll
      for (int nf = 0; nf < NF; ++nf) {
        const int cb = wcN * (NF * 16) + nf * 16 + fr;
        atomicAdd(&red[cb], ps[nf]);
        atomicAdd(&red[64 + cb], pq[nf]);
      }
    }
    __syncthreads();
    if (tid < 64) {
      atomicAdd(&sS[n0 + tid], red[tid]);
      atomicAdd(&sQ[n0 + tid], red[64 + tid]);
    }
  } else {
    // split-K offset epilogue
#pragma unroll
    for (int mf = 0; mf < 2; ++mf) {
      const int rr = m0 + wrM * 32 + mf * 16 + kg * 4;
#pragma unroll
      for (int nf = 0; nf < NF; ++nf) {
        const int col = n0 + wcN * (NF * 16) + nf * 16 + fr;
        if (col < 18) {
#pragma unroll
          for (int r = 0; r < 4; ++r)
            atomicAdd(&offout[(size_t)(rr + r) * 18 + col], acc[mf][nf][r]);
        }
      }
    }
  }
}

// ---------------- act = bf16(relu(bn1(in))), affine hoisted to LDS -----------
__global__ __launch_bounds__(256) void a1_kb(const bf16* __restrict__ in,
                                             const float* __restrict__ s,
                                             const float* __restrict__ sq,
                                             const float* __restrict__ g,
                                             const float* __restrict__ be,
                                             bf16* __restrict__ out) {
  __shared__ float scs[256], bis[256];
  const int tid = threadIdx.x;
  {
    const float inv = 1.f / (float)MM;
    const float mean = s[tid] * inv;
    const float var = sq[tid] * inv - mean * mean;
    const float sc = g[tid] * rsqrtf(var + 1e-5f);
    scs[tid] = sc;
    bis[tid] = be[tid] - mean * sc;
  }
  __syncthreads();
  const size_t idx = (size_t)(blockIdx.x * 256 + tid) * 8;
  const int c0 = (int)(idx & 255);
  bf16x8 v = *(const bf16x8*)&in[idx];
  bf16x8 o;
#pragma unroll
  for (int i = 0; i < 8; ++i) {
    float r = (float)v[i] * scs[c0 + i] + bis[c0 + i];
    o[i] = (bf16)(r > 0.f ? r : 0.f);
  }
  *(bf16x8*)&out[idx] = o;
}

// ---------------- out = relu(bn2(o2) + x), bf16 NHWC -> f32 NCHW -------------
__global__ __launch_bounds__(256) void final_kb(const bf16* __restrict__ o2,
                                                const float* __restrict__ x,
                                                const float* __restrict__ s,
                                                const float* __restrict__ sq,
                                                const float* __restrict__ g,
                                                const float* __restrict__ be,
                                                float* __restrict__ out) {
  __shared__ float t[32][33];
  const int b = blockIdx.z, hw0 = blockIdx.x * 32, o0 = blockIdx.y * 32;
  const int tid = threadIdx.x;
  {
    const int hwl = tid >> 3, ol = (tid & 7) * 4;
    bf16x4 v = *(const bf16x4*)&o2[(size_t)(b * HW + hw0 + hwl) * CH + o0 + ol];
#pragma unroll
    for (int i = 0; i < 4; ++i) t[ol + i][hwl] = (float)v[i];
  }
  __syncthreads();
  const int ol = tid >> 3, hwl = (tid & 7) * 4;
  const int ch = o0 + ol;
  const float inv = 1.f / (float)MM;
  const float mean = s[ch] * inv;
  const float var = sq[ch] * inv - mean * mean;
  const float sc = g[ch] * rsqrtf(var + 1e-5f);
  const float bb = be[ch] - mean * sc;
  const size_t xi = (size_t)(b * CH + ch) * HW + hw0 + hwl;
  f32x4 xv = *(const f32x4*)&x[xi];
  f32x4 r;
#pragma unroll
  for (int i = 0; i < 4; ++i) {
    float v = t[ol][hwl + i] * sc + bb + xv[i];
    r[i] = v > 0.f ? v : 0.f;
  }
  *(f32x4*)&out[xi] = r;
}

// ---------------- workspace layout (bytes) ----------------
#define WS_XN 0ULL            // xn NHWC bf16:        6,422,528
#define WS_W1T 6422528ULL     // w1t bf16:            1,179,648
#define WS_W2T 7602176ULL     // w2t bf16:            1,179,648
#define WS_WOF 8781824ULL     // wof bf16 pad64:        294,912
#define WS_OFFB 9076736ULL    // offb f32 [m][18]:      903,168
#define WS_A1 9979904ULL      // A1 bf16 [m][2304]:  57,802,752
#define WS_O1 67782656ULL     // out1 bf16 NHWC:      6,422,528
#define WS_ACT 74205184ULL    // act bf16 NHWC:       6,422,528
#define WS_O2 80627712ULL     // out2 bf16 NHWC:      6,422,528
#define WS_ZP 87050240ULL     // zero page:               4,096
#define WS_STAT 87054336ULL   // s1,sq1,s2,sq2:           4,096
// total: 87,058,432

extern "C" void kernel_launch(void* const* d_in, const int* in_sizes, int n_in,
                              void* d_out, int out_size, void* d_ws, size_t ws_size,
                              hipStream_t stream) {
  const float* x = (const float*)d_in[0];
  const float* w_off = (const float*)d_in[1];
  const float* b_off = (const float*)d_in[2];
  const float* w1 = (const float*)d_in[3];
  const float* g1 = (const float*)d_in[4];
  const float* be1 = (const float*)d_in[5];
  const float* w2 = (const float*)d_in[6];
  const float* g2 = (const float*)d_in[7];
  const float* be2 = (const float*)d_in[8];
  float* out = (float*)d_out;
  char* ws = (char*)d_ws;

  bf16* xn = (bf16*)(ws + WS_XN);
  bf16* w1t = (bf16*)(ws + WS_W1T);
  bf16* w2t = (bf16*)(ws + WS_W2T);
  bf16* wof = (bf16*)(ws + WS_WOF);
  float* offb = (float*)(ws + WS_OFFB);
  bf16* A1 = (bf16*)(ws + WS_A1);
  bf16* o1 = (bf16*)(ws + WS_O1);
  bf16* act = (bf16*)(ws + WS_ACT);
  bf16* o2 = (bf16*)(ws + WS_O2);
  bf16* zp = (bf16*)(ws + WS_ZP);
  float* s1 = (float*)(ws + WS_STAT);
  float* sq1 = (float*)(ws + WS_STAT + 1024);
  float* s2 = (float*)(ws + WS_STAT + 2048);
  float* sq2 = (float*)(ws + WS_STAT + 3072);

  hipMemsetAsync(ws + WS_ZP, 0, 8192, stream);      // zp + stats
  hipMemsetAsync(ws + WS_OFFB, 0, 903168, stream);  // offset split-K accum

  // transpose + all weight reorders (3136 + 4608 + 576 blocks)
  prep_k<<<8320, 256, 0, stream>>>(x, xn, w1, w2, w_off, w1t, w2t, wof);

  // offset conv: implicit im2col (dil2,pad2), TN=32, split-K=4 -> offb
  gemm_k<1, 0, 0, 32, 9><<<dim3(1, 196, 4), 256, 0, stream>>>(
      xn, wof, zp, nullptr, nullptr, nullptr, offb, 2, 2);

  // deform sample -> A1
  build_deform_k<<<784, 256, 0, stream>>>(xn, offb, b_off, A1);

  // deform GEMM: linear A1, full-K, XCD-swizzled -> o1 bf16 (+stats)
  gemm_k<0, 1, 1, 64, 36><<<dim3(784), 256, 0, stream>>>(
      A1, w1t, zp, o1, s1, sq1, nullptr, 0, 0);
  a1_kb<<<1568, 256, 0, stream>>>(o1, s1, sq1, g1, be1, act);

  // conv2: implicit im2col (dil1,pad1), full-K, XCD-swizzled -> o2 bf16 (+stats)
  gemm_k<1, 1, 1, 64, 36><<<dim3(784), 256, 0, stream>>>(
      act, w2t, zp, o2, s2, sq2, nullptr, 1, 1);

  final_kb<<<dim3(98, 8, 4), 256, 0, stream>>>(o2, x, s2, sq2, g2, be2, out);
}